// Round 1
// baseline (377.780 us; speedup 1.0000x reference)
//
#include <hip/hip_runtime.h>

#define M1   33            // LPC_ORDER + 1
#define RPT  4             // rows per thread: 4*33*4B = 528 B contiguous, 16B-aligned per lane
#define BLK  64            // one wave per block; no barriers needed anywhere
#define FPT  (RPT * M1)    // 132 floats per thread
#define VPT  (FPT / 4)     // 33 float4 per thread

// No LDS, no __syncthreads. Each thread owns 4 consecutive rows (528 contiguous
// bytes), loaded as 33 independent global_load_dwordx4 with immediate offsets.
// L1 absorbs the per-instruction stride (each 64B line is reused by the next
// 1-3 loads of the same lane). The 4 independent Levinson recursions give 4-way
// ILP on the serial dependence chain; 33 outstanding loads/lane give the memory
// system deep concurrency despite 3 waves/SIMD.
// __launch_bounds__(64,3): VGPR cap 170 — design needs ~132 data + ~20 overhead.
__global__ __launch_bounds__(BLK, 3)
void parcor_to_lpc_kernel(const float* __restrict__ k, float* __restrict__ out,
                          int nthreads) {
    const int tid = blockIdx.x * BLK + threadIdx.x;
    if (tid >= nthreads) return;

    const float4* __restrict__ src = (const float4*)k   + (size_t)tid * VPT;
    float4*       __restrict__ dst = (float4*)out       + (size_t)tid * VPT;

    union { float f[FPT]; float4 v[VPT]; } a;

    // ---- 33 independent 16B loads, contiguous 528 B per lane ----
    #pragma unroll
    for (int i = 0; i < VPT; ++i)
        a.v[i] = src[i];

    // ---- 4 interleaved Levinson step-up recursions (m outer, row inner:
    //      4 independent dep-chains in flight at every step) ----
    #pragma unroll
    for (int m = 2; m < M1; ++m) {
        #pragma unroll
        for (int r = 0; r < RPT; ++r) {
            float* ar = a.f + r * M1;
            const float km = ar[m];   // a[m] == k[m] still at step m
            #pragma unroll
            for (int j = 1; 2 * j < m; ++j) {
                const float x = ar[j];
                const float y = ar[m - j];
                ar[j]     = fmaf(km, y, x);
                ar[m - j] = fmaf(km, x, y);
            }
            if ((m & 1) == 0) {
                const int j = m >> 1;
                ar[j] = fmaf(km, ar[j], ar[j]);   // midpoint: a[j]*(1+km)
            }
        }
    }

    // ---- 33 independent 16B stores, same contiguous layout ----
    #pragma unroll
    for (int i = 0; i < VPT; ++i)
        dst[i] = a.v[i];
}

// Fallback for trailing rows (nrows % 4 != 0) — not hit for the 16x65536 shape.
__global__ void parcor_to_lpc_tail_kernel(const float* __restrict__ k,
                                          float* __restrict__ out,
                                          int row_start, int nrows) {
    const int row = row_start + blockIdx.x * blockDim.x + threadIdx.x;
    if (row >= nrows) return;
    const float* src = k + (size_t)row * M1;
    float* dst = out + (size_t)row * M1;
    float a[M1];
    #pragma unroll
    for (int j = 0; j < M1; ++j) a[j] = src[j];
    #pragma unroll
    for (int m = 2; m < M1; ++m) {
        const float km = a[m];
        #pragma unroll
        for (int j = 1; 2 * j < m; ++j) {
            const float x = a[j];
            const float y = a[m - j];
            a[j]     = fmaf(km, y, x);
            a[m - j] = fmaf(km, x, y);
        }
        if ((m & 1) == 0) {
            const int j = m >> 1;
            a[j] = fmaf(km, a[j], a[j]);
        }
    }
    #pragma unroll
    for (int j = 0; j < M1; ++j) dst[j] = a[j];
}

extern "C" void kernel_launch(void* const* d_in, const int* in_sizes, int n_in,
                              void* d_out, int out_size, void* d_ws, size_t ws_size,
                              hipStream_t stream) {
    const float* k = (const float*)d_in[0];
    float* out = (float*)d_out;

    const int nrows    = in_sizes[0] / M1;   // 16 * 65536 = 1,048,576
    const int nthreads = nrows / RPT;        // 262,144 fat threads
    const int rem_row0 = nthreads * RPT;
    const int rem      = nrows - rem_row0;

    if (nthreads > 0) {
        const int nblk = (nthreads + BLK - 1) / BLK;   // 4096 blocks
        parcor_to_lpc_kernel<<<nblk, BLK, 0, stream>>>(k, out, nthreads);
    }
    if (rem > 0)
        parcor_to_lpc_tail_kernel<<<(rem + 63) / 64, 64, 0, stream>>>(
            k, out, rem_row0, nrows);
}

// Round 2
// 239.824 us; speedup vs baseline: 1.5752x; 1.5752x over previous
//
#include <hip/hip_runtime.h>

#define M1      33                  // LPC_ORDER + 1
#define TROWS   64                  // rows per tile (= one wave, 1 row/thread)
#define BLK     64                  // single wave per block: no __syncthreads anywhere
#define TILE_F  (TROWS * M1)        // 2112 floats = 8448 B per tile
#define NLD     8                   // full-wave 16B global_load_lds per tile (+1 partial)
#define NST     8                   // full-wave 16B stores per tile (+1 partial)
#define PARTIAL 16                  // active lanes in the partial op (528 float4 = 8*64 + 16)
#define GRID    2304                // 9 blocks/CU * 256 CU (LDS 16.9 KB -> 9 resident)

typedef const __attribute__((address_space(1))) float* gptr_t;
typedef __attribute__((address_space(3))) float*       lptr_t;

// Stage one 8448 B tile global -> LDS, linear layout (wave-uniform base + lane*16).
// 9 vmcnt increments per call (8 full + 1 exec-masked, 16 lanes active).
__device__ __forceinline__ void stage_tile(const float* __restrict__ g,
                                           float* lds_base, int lane) {
    #pragma unroll
    for (int i = 0; i < NLD; ++i)
        __builtin_amdgcn_global_load_lds((gptr_t)(g + i * 256 + lane * 4),
                                         (lptr_t)(lds_base + i * 256), 16, 0, 0);
    if (lane < PARTIAL)
        __builtin_amdgcn_global_load_lds((gptr_t)(g + NLD * 256 + lane * 4),
                                         (lptr_t)(lds_base + NLD * 256), 16, 0, 0);
}

// Persistent single-wave blocks, double-buffered LDS, counted-vmcnt pipeline:
// while computing tile i from buf, tile i+1 streams into buf^1. Steady-state
// wait is vmcnt(9) (prev tile's 9 stores may remain in flight; vmcnt retires
// in-order) -- never a full drain inside the loop.
__global__ __launch_bounds__(BLK)
void parcor_to_lpc_kernel(const float* __restrict__ k, float* __restrict__ out,
                          int ntiles) {
    __shared__ __align__(16) float lds[2 * TILE_F];   // 16.9 KB -> 9 blocks/CU
    const int lane = threadIdx.x;

    int tile = blockIdx.x;
    if (tile >= ntiles) return;
    const int stride = gridDim.x;

    stage_tile(k + (size_t)tile * TILE_F, &lds[0], lane);

    int buf = 0;
    bool first = true;
    while (true) {
        const int next = tile + stride;

        // Wait for current tile's 9 loads (oldest outstanding). Steady state
        // leaves the previous tile's 9 stores in flight.
        if (first) { asm volatile("s_waitcnt vmcnt(0)" ::: "memory"); first = false; }
        else       { asm volatile("s_waitcnt vmcnt(9)" ::: "memory"); }

        // Prefetch next tile into the other buffer; overlaps all of compute+store.
        if (next < ntiles)
            stage_tile(k + (size_t)next * TILE_F, &lds[(buf ^ 1) * TILE_F], lane);

        float* L = &lds[buf * TILE_F];

        // LDS -> registers: row stride 33 => bank (lane+j)%32, 2-way alias = free.
        float a[M1];
        #pragma unroll
        for (int j = 0; j < M1; ++j) a[j] = L[lane * M1 + j];

        // Levinson step-up recursion, fully unrolled, in registers.
        #pragma unroll
        for (int m = 2; m < M1; ++m) {
            const float km = a[m];
            #pragma unroll
            for (int j = 1; 2 * j < m; ++j) {
                const float x = a[j];
                const float y = a[m - j];
                a[j]     = fmaf(km, y, x);
                a[m - j] = fmaf(km, x, y);
            }
            if ((m & 1) == 0) {
                const int j = m >> 1;
                a[j] = fmaf(km, a[j], a[j]);   // midpoint: a[j]*(1+km)
            }
        }

        // registers -> LDS (own row), then cross-lane coalesced store.
        #pragma unroll
        for (int j = 0; j < M1; ++j) L[lane * M1 + j] = a[j];

        // Single wave: lgkmcnt(0) makes all 64 lanes' ds_writes visible to the
        // cross-lane b128 reads below (no s_barrier => no vmcnt(0) drain).
        asm volatile("s_waitcnt lgkmcnt(0)" ::: "memory");

        const float4* l4 = (const float4*)L;
        float4* g4 = (float4*)(out + (size_t)tile * TILE_F);
        #pragma unroll
        for (int i = 0; i < NST; ++i)
            g4[i * BLK + lane] = l4[i * BLK + lane];
        if (lane < PARTIAL)
            g4[NST * BLK + lane] = l4[NST * BLK + lane];

        if (next >= ntiles) break;
        tile = next;
        buf ^= 1;
    }
}

// Fallback for trailing rows (nrows % 64 != 0) -- not hit for 16x65536.
__global__ void parcor_to_lpc_tail_kernel(const float* __restrict__ k,
                                          float* __restrict__ out,
                                          int row_start, int nrows) {
    const int row = row_start + blockIdx.x * blockDim.x + threadIdx.x;
    if (row >= nrows) return;
    const float* src = k + (size_t)row * M1;
    float* dst = out + (size_t)row * M1;
    float a[M1];
    #pragma unroll
    for (int j = 0; j < M1; ++j) a[j] = src[j];
    #pragma unroll
    for (int m = 2; m < M1; ++m) {
        const float km = a[m];
        #pragma unroll
        for (int j = 1; 2 * j < m; ++j) {
            const float x = a[j];
            const float y = a[m - j];
            a[j]     = fmaf(km, y, x);
            a[m - j] = fmaf(km, x, y);
        }
        if ((m & 1) == 0) {
            const int j = m >> 1;
            a[j] = fmaf(km, a[j], a[j]);
        }
    }
    #pragma unroll
    for (int j = 0; j < M1; ++j) dst[j] = a[j];
}

extern "C" void kernel_launch(void* const* d_in, const int* in_sizes, int n_in,
                              void* d_out, int out_size, void* d_ws, size_t ws_size,
                              hipStream_t stream) {
    const float* k = (const float*)d_in[0];
    float* out = (float*)d_out;

    const int nrows     = in_sizes[0] / M1;    // 16 * 65536 = 1,048,576
    const int ntiles    = nrows / TROWS;       // 16384 tiles
    const int tile_rows = ntiles * TROWS;
    const int rem       = nrows - tile_rows;

    if (ntiles > 0) {
        const int grid = ntiles < GRID ? ntiles : GRID;
        parcor_to_lpc_kernel<<<grid, BLK, 0, stream>>>(k, out, ntiles);
    }
    if (rem > 0)
        parcor_to_lpc_tail_kernel<<<(rem + 63) / 64, 64, 0, stream>>>(
            k, out, tile_rows, nrows);
}